// Round 1
// baseline (465.094 us; speedup 1.0000x reference)
//
#include <hip/hip_runtime.h>
#include <hip/hip_bf16.h>
#include <stdint.h>
#include <stddef.h>

// Problem constants (from reference): N=2048, C=512, E=8192
#define NN 2048
#define CD 512
#define EE 8192

typedef unsigned short u16;
typedef __attribute__((ext_vector_type(8))) short short8;   // 8 x bf16 (4 VGPRs) MFMA A/B frag
typedef __attribute__((ext_vector_type(4))) float floatx4;  // MFMA C/D frag

__device__ inline u16 f2bf(float f) {
    uint32_t u = __float_as_uint(f);
    u += 0x7FFFu + ((u >> 16) & 1u);   // round-to-nearest-even
    return (u16)(u >> 16);
}
__device__ inline float bf2f(u16 h) { return __uint_as_float(((uint32_t)h) << 16); }

// ---------------------------------------------------------------------------
// prep: convert inputs to bf16 (+ transpose root, pack W_att1 slices)
// Segments (element counts):
//   xb 1048576 | eb 4194304 | Wnnb 262144 | Wlinb 262144 | rootTb 262144 | Wpackb 786432
// total = 6815744 elems -> 26624 blocks x 256
// ---------------------------------------------------------------------------
__global__ __launch_bounds__(256) void prep_kernel(
    const float* __restrict__ x, const float* __restrict__ ea,
    const float* __restrict__ Wnn, const float* __restrict__ Wlin,
    const float* __restrict__ root, const float* __restrict__ Watt1,
    u16* __restrict__ xb, u16* __restrict__ eb, u16* __restrict__ Wnnb,
    u16* __restrict__ Wlinb, u16* __restrict__ rootTb, u16* __restrict__ Wpackb)
{
    size_t idx = (size_t)blockIdx.x * 256 + threadIdx.x;
    if (idx < 1048576) { xb[idx] = f2bf(x[idx]); return; }
    idx -= 1048576;
    if (idx < 4194304) { eb[idx] = f2bf(ea[idx]); return; }
    idx -= 4194304;
    if (idx < 262144) { Wnnb[idx] = f2bf(Wnn[idx]); return; }
    idx -= 262144;
    if (idx < 262144) { Wlinb[idx] = f2bf(Wlin[idx]); return; }
    idx -= 262144;
    if (idx < 262144) {  // rootT[c][k] = root[k][c]
        int c = (int)(idx >> 9), k = (int)(idx & 511);
        rootTb[idx] = f2bf(root[(size_t)k * 512 + c]); return;
    }
    idx -= 262144;
    {   // Wpackb[cp][k] = W_att1[cp%512][ (cp/512)*512 + k ], cp in [0,1536)
        int cp = (int)(idx >> 9), k = (int)(idx & 511);
        int s = cp >> 9, c = cp & 511;
        Wpackb[idx] = f2bf(Watt1[(size_t)c * 1536 + s * 512 + k]);
    }
}

// ---------------------------------------------------------------------------
// bf16 MFMA GEMM:  C[M,Nc] = A[M,512] * B[Nc,512]^T (+bias[col])
// 2-barrier K-loop, global_load_lds width 16, 4 waves in 2x2, 16x16x32 MFMA.
// ---------------------------------------------------------------------------
template<int BM, int BN, bool OUT_BF16, bool BIAS>
__global__ __launch_bounds__(256) void gemm_bt(
    const u16* __restrict__ A, const u16* __restrict__ B,
    void* __restrict__ Cout, const float* __restrict__ bias, int Nc)
{
    constexpr int K = 512, BK = 32;
    __shared__ __align__(16) u16 As[BM * BK];
    __shared__ __align__(16) u16 Bs[BN * BK];
    const int tid = threadIdx.x;
    const int bm = blockIdx.x, bn = blockIdx.y;
    const int wave = tid >> 6, lane = tid & 63;
    const int wm = wave >> 1, wn = wave & 1;
    constexpr int WM = BM / 2, WN = BN / 2;
    constexpr int FM = WM / 16, FN = WN / 16;
    const int lrow = lane & 15, lk = lane >> 4;
    floatx4 acc[FM][FN] = {};
    constexpr int ALOADS = (BM * BK) / (256 * 8);
    constexpr int BLOADS = (BN * BK) / (256 * 8);

    for (int k0 = 0; k0 < K; k0 += BK) {
        __syncthreads();  // previous iter's LDS reads done before overwrite
#pragma unroll
        for (int c = 0; c < ALOADS; ++c) {
            int e = c * 2048 + tid * 8;
            int row = e >> 5, col = e & 31;
            __builtin_amdgcn_global_load_lds(
                (const __attribute__((address_space(1))) void*)(A + (size_t)(bm * BM + row) * K + k0 + col),
                (__attribute__((address_space(3))) void*)(&As[e]), 16, 0, 0);
        }
#pragma unroll
        for (int c = 0; c < BLOADS; ++c) {
            int e = c * 2048 + tid * 8;
            int row = e >> 5, col = e & 31;
            __builtin_amdgcn_global_load_lds(
                (const __attribute__((address_space(1))) void*)(B + (size_t)(bn * BN + row) * K + k0 + col),
                (__attribute__((address_space(3))) void*)(&Bs[e]), 16, 0, 0);
        }
        __syncthreads();  // drains vmcnt: staged tile visible

        short8 af[FM], bfr[FN];
#pragma unroll
        for (int i = 0; i < FM; ++i)
            af[i] = *(const short8*)(&As[(wm * WM + i * 16 + lrow) * BK + lk * 8]);
#pragma unroll
        for (int j = 0; j < FN; ++j)
            bfr[j] = *(const short8*)(&Bs[(wn * WN + j * 16 + lrow) * BK + lk * 8]);
#pragma unroll
        for (int i = 0; i < FM; ++i)
#pragma unroll
            for (int j = 0; j < FN; ++j)
                acc[i][j] = __builtin_amdgcn_mfma_f32_16x16x32_bf16(af[i], bfr[j], acc[i][j], 0, 0, 0);
    }

#pragma unroll
    for (int i = 0; i < FM; ++i) {
#pragma unroll
        for (int j = 0; j < FN; ++j) {
            const int col = bn * BN + wn * WN + j * 16 + lrow;
            const float bv = BIAS ? bias[col] : 0.0f;
#pragma unroll
            for (int r = 0; r < 4; ++r) {
                const int row = bm * BM + wm * WM + i * 16 + lk * 4 + r;
                const float v = acc[i][j][r] + bv;
                if (OUT_BF16) ((u16*)Cout)[(size_t)row * Nc + col] = f2bf(v);
                else          ((float*)Cout)[(size_t)row * Nc + col] = v;
            }
        }
    }
}

// ---------------------------------------------------------------------------
// edge score: s[e] = leaky_relu( dot(tanh(G1[dst]+G2[src]+G3[e]+b_att1), w_att2), 0.2 )
// one 256-thread block per edge
// ---------------------------------------------------------------------------
__global__ __launch_bounds__(256) void edge_score(
    const float* __restrict__ G12, const float* __restrict__ G3,
    const int* __restrict__ ei, const float* __restrict__ batt1,
    const float* __restrict__ watt2, float* __restrict__ sOut)
{
    const int e = blockIdx.x;
    const int src = ei[e];
    const int dst = ei[EE + e];
    const int tid = threadIdx.x;
    const float* g1 = G12 + (size_t)dst * 1024;
    const float* g2 = G12 + (size_t)src * 1024 + 512;
    const float* g3 = G3 + (size_t)e * 512;
    float partial = 0.0f;
#pragma unroll
    for (int c = tid; c < 512; c += 256) {
        float v = tanhf(g1[c] + g2[c] + g3[c] + batt1[c]);
        partial += v * watt2[c];
    }
    for (int o = 32; o; o >>= 1) partial += __shfl_down(partial, o);
    __shared__ float red[4];
    if ((tid & 63) == 0) red[tid >> 6] = partial;
    __syncthreads();
    if (tid == 0) {
        float sv = red[0] + red[1] + red[2] + red[3];
        sOut[e] = (sv >= 0.0f) ? sv : 0.2f * sv;
    }
}

// ---------------------------------------------------------------------------
// global max of s + p[j] = exp(s[j]-M)   (single block)
// ---------------------------------------------------------------------------
__global__ __launch_bounds__(1024) void softmax_prep(
    const float* __restrict__ s, float* __restrict__ p)
{
    const int tid = threadIdx.x;
    float m = -3.0e38f;
    for (int j = tid; j < EE; j += 1024) m = fmaxf(m, s[j]);
    for (int o = 32; o; o >>= 1) m = fmaxf(m, __shfl_down(m, o));
    __shared__ float red[16];
    if ((tid & 63) == 0) red[tid >> 6] = m;
    __syncthreads();
    float M = red[0];
#pragma unroll
    for (int k = 1; k < 16; ++k) M = fmaxf(M, red[k]);
    for (int j = tid; j < EE; j += 1024) p[j] = __expf(s[j] - M);
}

// ---------------------------------------------------------------------------
// att[i] = mask[i][i] ? p[i] / sum_j(mask[i][j]*p[j]) : 0   (1 block per row)
// The -10000 fill contributes exp(-10000-M)=0 in f32, identical to the ref.
// ---------------------------------------------------------------------------
__global__ __launch_bounds__(256) void lse_att(
    const unsigned char* __restrict__ mask, const float* __restrict__ p,
    float* __restrict__ att)
{
    const int i = blockIdx.x;
    const int tid = threadIdx.x;
    const unsigned char* row = mask + (size_t)i * EE;
    float sum = 0.0f;
#pragma unroll
    for (int c = 0; c < 2; ++c) {
        const int base = c * 4096 + tid * 16;
        uint4 mw = *(const uint4*)(row + base);
        uint32_t w[4] = { mw.x, mw.y, mw.z, mw.w };
#pragma unroll
        for (int q = 0; q < 4; ++q) {
            float4 pv = *(const float4*)(p + base + q * 4);
            uint32_t b = w[q];
            sum += pv.x * (float)(b & 1u);
            sum += pv.y * (float)((b >> 8) & 1u);
            sum += pv.z * (float)((b >> 16) & 1u);
            sum += pv.w * (float)((b >> 24) & 1u);
        }
    }
    for (int o = 32; o; o >>= 1) sum += __shfl_down(sum, o);
    __shared__ float red[4];
    if ((tid & 63) == 0) red[tid >> 6] = sum;
    __syncthreads();
    if (tid == 0) {
        float total = red[0] + red[1] + red[2] + red[3];
        unsigned char diag = mask[(size_t)i * EE + i];
        float a;
        if (total > 0.0f) a = diag ? (p[i] / total) : 0.0f;
        else              a = 1.0f / (float)EE;  // all-false row (ref edge case)
        att[i] = a;
    }
}

// ---------------------------------------------------------------------------
// scatter: OUT1[dst] += att[e] * H[src]   (f32 atomics; skip att==0 edges)
// ---------------------------------------------------------------------------
__global__ __launch_bounds__(256) void aggr_kernel(
    const u16* __restrict__ Hb, const int* __restrict__ ei,
    const float* __restrict__ att, float* __restrict__ OUT1)
{
    const int e = blockIdx.x;
    const float a = att[e];
    if (a == 0.0f) return;
    const int src = ei[e];
    const int dst = ei[EE + e];
    const u16* h = Hb + (size_t)src * 512;
    float* o = OUT1 + (size_t)dst * 512;
    for (int c = threadIdx.x; c < 512; c += 256)
        atomicAdd(o + c, a * bf2f(h[c]));
}

// ---------------------------------------------------------------------------
// LayerNorm over C=512 (1 block per row, 2 elems per thread)
// RESID: normalize (in + resid); WRITE_BF16: also write bf16 copy
// ---------------------------------------------------------------------------
template<bool RESID, bool WRITE_BF16>
__global__ __launch_bounds__(256) void ln_kernel(
    const float* __restrict__ in, const float* __restrict__ resid,
    const float* __restrict__ gamma, const float* __restrict__ beta,
    float* __restrict__ outF, u16* __restrict__ outB)
{
    const int n = blockIdx.x, tid = threadIdx.x;
    const size_t rowoff = (size_t)n * 512;
    float2 v = *(const float2*)(in + rowoff + tid * 2);
    float a0 = v.x, a1 = v.y;
    if (RESID) {
        float2 r = *(const float2*)(resid + rowoff + tid * 2);
        a0 += r.x; a1 += r.y;
    }
    float sum = a0 + a1, sq = a0 * a0 + a1 * a1;
    for (int o = 32; o; o >>= 1) {
        sum += __shfl_down(sum, o);
        sq  += __shfl_down(sq, o);
    }
    __shared__ float rs_[4], rq_[4];
    if ((tid & 63) == 0) { rs_[tid >> 6] = sum; rq_[tid >> 6] = sq; }
    __syncthreads();
    sum = rs_[0] + rs_[1] + rs_[2] + rs_[3];
    sq  = rq_[0] + rq_[1] + rq_[2] + rq_[3];
    const float mean = sum * (1.0f / 512.0f);
    const float var  = sq * (1.0f / 512.0f) - mean * mean;
    const float rstd = rsqrtf(var + 1e-5f);
    const int c0 = tid * 2;
    const float y0 = (a0 - mean) * rstd * gamma[c0]     + beta[c0];
    const float y1 = (a1 - mean) * rstd * gamma[c0 + 1] + beta[c0 + 1];
    *(float2*)(outF + rowoff + c0) = make_float2(y0, y1);
    if (WRITE_BF16) { outB[rowoff + c0] = f2bf(y0); outB[rowoff + c0 + 1] = f2bf(y1); }
}

// ---------------------------------------------------------------------------
extern "C" void kernel_launch(void* const* d_in, const int* in_sizes, int n_in,
                              void* d_out, int out_size, void* d_ws, size_t ws_size,
                              hipStream_t stream)
{
    const float* x     = (const float*)d_in[0];
    const int*   ei    = (const int*)d_in[1];          // int32 (JAX x64 disabled)
    const float* ea    = (const float*)d_in[2];
    const unsigned char* mask = (const unsigned char*)d_in[3];  // numpy bool = 1 byte
    const float* Wnn   = (const float*)d_in[4];
    const float* bnn   = (const float*)d_in[5];
    const float* Watt1 = (const float*)d_in[6];
    const float* batt1 = (const float*)d_in[7];
    const float* watt2 = (const float*)d_in[8];
    const float* root  = (const float*)d_in[9];
    const float* bias  = (const float*)d_in[10];
    const float* gam1  = (const float*)d_in[11];
    const float* bet1  = (const float*)d_in[12];
    const float* gam2  = (const float*)d_in[13];
    const float* bet2  = (const float*)d_in[14];
    const float* Wlin  = (const float*)d_in[15];
    const float* blin  = (const float*)d_in[16];
    float* out = (float*)d_out;

    char* w = (char*)d_ws;
    auto take = [&](size_t bytes) -> char* {
        char* pp = w;
        w += (bytes + 255) & ~(size_t)255;
        return pp;
    };
    u16*   xb     = (u16*)take((size_t)NN * CD * 2);
    u16*   eb     = (u16*)take((size_t)EE * CD * 2);
    u16*   Wnnb   = (u16*)take((size_t)CD * CD * 2);
    u16*   Wlinb  = (u16*)take((size_t)CD * CD * 2);
    u16*   rootTb = (u16*)take((size_t)CD * CD * 2);
    u16*   Wpb    = (u16*)take((size_t)3 * CD * CD * 2);
    u16*   Hb     = (u16*)take((size_t)NN * CD * 2);
    u16*   HEb    = (u16*)take((size_t)EE * CD * 2);
    float* G12    = (float*)take((size_t)NN * 1024 * 4);
    float* G3     = (float*)take((size_t)EE * CD * 4);
    float* OUT1   = (float*)take((size_t)NN * CD * 4);
    float* sbuf   = (float*)take((size_t)EE * 4);
    float* pbuf   = (float*)take((size_t)EE * 4);
    float* attb   = (float*)take((size_t)EE * 4);
    float* x1     = (float*)take((size_t)NN * CD * 4);
    u16*   x1b    = (u16*)take((size_t)NN * CD * 2);
    float* Tbuf   = (float*)take((size_t)NN * CD * 4);

    // 1. convert/pack
    prep_kernel<<<26624, 256, 0, stream>>>(x, ea, Wnn, Wlin, root, Watt1,
                                           xb, eb, Wnnb, Wlinb, rootTb, Wpb);
    // 2. H = x@Wnn^T + bnn  (bf16 out)
    gemm_bt<64, 128, true, true><<<dim3(32, 4), 256, 0, stream>>>(xb, Wnnb, Hb, bnn, 512);
    // 3. HE = edge_attr@Wnn^T + bnn (bf16 out)
    gemm_bt<128, 128, true, true><<<dim3(64, 4), 256, 0, stream>>>(eb, Wnnb, HEb, bnn, 512);
    // 4. G12 = H @ [A1;A2]^T  ([N,1024] f32)
    gemm_bt<64, 128, false, false><<<dim3(32, 8), 256, 0, stream>>>(Hb, Wpb, G12, nullptr, 1024);
    // 5. G3 = HE @ A3^T ([E,512] f32)
    gemm_bt<128, 128, false, false><<<dim3(64, 4), 256, 0, stream>>>(HEb, Wpb + (size_t)1024 * 512, G3, nullptr, 512);
    // 6. OUT1 = x @ root + bias (f32)
    gemm_bt<64, 128, false, true><<<dim3(32, 4), 256, 0, stream>>>(xb, rootTb, OUT1, bias, 512);
    // 7. edge scores
    edge_score<<<EE, 256, 0, stream>>>(G12, G3, ei, batt1, watt2, sbuf);
    // 8. p = exp(s - max(s))
    softmax_prep<<<1, 1024, 0, stream>>>(sbuf, pbuf);
    // 9. att from masked sums (the E x E scan)
    lse_att<<<EE, 256, 0, stream>>>(mask, pbuf, attb);
    // 10. scatter aggregation into OUT1
    aggr_kernel<<<EE, 256, 0, stream>>>(Hb, ei, attb, OUT1);
    // 11. x1 = LN(OUT1) (f32 + bf16)
    ln_kernel<false, true><<<NN, 256, 0, stream>>>(OUT1, nullptr, gam1, bet1, x1, x1b);
    // 12. T = x1 @ Wlin^T + blin
    gemm_bt<64, 128, false, true><<<dim3(32, 4), 256, 0, stream>>>(x1b, Wlinb, Tbuf, blin, 512);
    // 13. out = LN(x1 + T)
    ln_kernel<true, false><<<NN, 256, 0, stream>>>(Tbuf, x1, gam2, bet2, out, nullptr);
}

// Round 2
// 457.881 us; speedup vs baseline: 1.0158x; 1.0158x over previous
//
#include <hip/hip_runtime.h>
#include <stdint.h>
#include <stddef.h>

// Problem constants: N=2048, C=512, E=8192
#define NN 2048
#define CD 512
#define EE 8192

typedef unsigned short u16;
typedef __attribute__((ext_vector_type(8))) short short8;   // 8 x bf16 MFMA A/B frag
typedef __attribute__((ext_vector_type(4))) float floatx4;  // MFMA C/D frag

__device__ inline u16 f2bf(float f) {
    uint32_t u = __float_as_uint(f);
    u += 0x7FFFu + ((u >> 16) & 1u);   // RNE
    return (u16)(u >> 16);
}
__device__ inline float bf2f(u16 h) { return __uint_as_float(((uint32_t)h) << 16); }

// ---------------------------------------------------------------------------
// prep: bf16 conversions + transposes + W_att1 pack. 4 elems/thread.
// Segments (elems): xb 1048576 | eb 4194304 | Wnn->Bcat[0:512) 262144 |
//   rootT->Bcat[512:1024) 262144 | WnnT 262144 | Wlin 262144 | Wpack 786432
// total 7077888 elems / 4 = 1769472 threads -> 6912 blocks
// ---------------------------------------------------------------------------
__global__ __launch_bounds__(256) void prep_kernel(
    const float* __restrict__ x, const float* __restrict__ ea,
    const float* __restrict__ Wnn, const float* __restrict__ Wlin,
    const float* __restrict__ root, const float* __restrict__ Watt1,
    u16* __restrict__ xb, u16* __restrict__ eb, u16* __restrict__ Bcat,
    u16* __restrict__ WnnTb, u16* __restrict__ Wlinb, u16* __restrict__ Wpackb)
{
    size_t i4 = ((size_t)blockIdx.x * 256 + threadIdx.x) * 4;
    auto cvt4 = [](const float* src, u16* dst, size_t idx) {
        float4 v = *(const float4*)(src + idx);
        ushort4 o; o.x = f2bf(v.x); o.y = f2bf(v.y); o.z = f2bf(v.z); o.w = f2bf(v.w);
        *(ushort4*)(dst + idx) = o;
    };
    if (i4 < 1048576) { cvt4(x, xb, i4); return; }
    i4 -= 1048576;
    if (i4 < 4194304) { cvt4(ea, eb, i4); return; }
    i4 -= 4194304;
    if (i4 < 262144) { cvt4(Wnn, Bcat, i4); return; }          // Bcat rows 0..511 = Wnn
    i4 -= 262144;
    if (i4 < 262144) {                                          // Bcat rows 512..1023 = root^T
        int c = (int)(i4 >> 9), k = (int)(i4 & 511);
        ushort4 o;
        o.x = f2bf(root[(size_t)(k + 0) * 512 + c]);
        o.y = f2bf(root[(size_t)(k + 1) * 512 + c]);
        o.z = f2bf(root[(size_t)(k + 2) * 512 + c]);
        o.w = f2bf(root[(size_t)(k + 3) * 512 + c]);
        *(ushort4*)(Bcat + 262144 + i4) = o; return;
    }
    i4 -= 262144;
    if (i4 < 262144) {                                          // WnnT[k][t] = Wnn[t][k]
        int k = (int)(i4 >> 9), t = (int)(i4 & 511);
        ushort4 o;
        o.x = f2bf(Wnn[(size_t)(t + 0) * 512 + k]);
        o.y = f2bf(Wnn[(size_t)(t + 1) * 512 + k]);
        o.z = f2bf(Wnn[(size_t)(t + 2) * 512 + k]);
        o.w = f2bf(Wnn[(size_t)(t + 3) * 512 + k]);
        *(ushort4*)(WnnTb + i4) = o; return;
    }
    i4 -= 262144;
    if (i4 < 262144) { cvt4(Wlin, Wlinb, i4); return; }
    i4 -= 262144;
    {   // Wpack[cp][t] = Watt1[cp&511][(cp>>9)*512 + t]  (rows: A1(512); A2(512); A3(512))
        int cp = (int)(i4 >> 9), t = (int)(i4 & 511);
        const float* sp = Watt1 + (size_t)(cp & 511) * 1536 + (cp >> 9) * 512 + t;
        float4 v = *(const float4*)sp;
        ushort4 o; o.x = f2bf(v.x); o.y = f2bf(v.y); o.z = f2bf(v.z); o.w = f2bf(v.w);
        *(ushort4*)(Wpackb + i4) = o;
    }
}

// ---------------------------------------------------------------------------
// bb[c] = b_att1[c] + sum_t Watt1[c,t] * bnn[t%512]   (full f32 precision)
// ---------------------------------------------------------------------------
__global__ __launch_bounds__(256) void bbvec_kernel(
    const float* __restrict__ Watt1, const float* __restrict__ bnn,
    const float* __restrict__ batt1, float* __restrict__ bb)
{
    const int c = blockIdx.x, tid = threadIdx.x;
    const float* row = Watt1 + (size_t)c * 1536;
    float partial = 0.0f;
#pragma unroll
    for (int t = tid; t < 1536; t += 256) partial += row[t] * bnn[t & 511];
    for (int o = 32; o; o >>= 1) partial += __shfl_down(partial, o);
    __shared__ float red[4];
    if ((tid & 63) == 0) red[tid >> 6] = partial;
    __syncthreads();
    if (tid == 0) bb[c] = batt1[c] + red[0] + red[1] + red[2] + red[3];
}

// ---------------------------------------------------------------------------
// shared MFMA K-loop: acc += A_tile * B_tile^T over K=512, BK=32
// ---------------------------------------------------------------------------
template<int BM, int BN>
__device__ inline void gemm_core(const u16* __restrict__ A, const u16* __restrict__ B,
                                 int bm, int bn, int tid, u16* As, u16* Bs,
                                 floatx4 (&acc)[BM / 32][BN / 32])
{
    constexpr int K = 512, BK = 32, WM = BM / 2, WN = BN / 2, FM = WM / 16, FN = WN / 16;
    const int wave = tid >> 6, lane = tid & 63;
    const int wm = wave >> 1, wn = wave & 1;
    const int lrow = lane & 15, lk = lane >> 4;
    constexpr int ALOADS = (BM * BK) / (256 * 8);
    constexpr int BLOADS = (BN * BK) / (256 * 8);
    for (int k0 = 0; k0 < K; k0 += BK) {
        __syncthreads();
#pragma unroll
        for (int c = 0; c < ALOADS; ++c) {
            int e = c * 2048 + tid * 8;
            int row = e >> 5, col = e & 31;
            __builtin_amdgcn_global_load_lds(
                (const __attribute__((address_space(1))) void*)(A + (size_t)(bm * BM + row) * K + k0 + col),
                (__attribute__((address_space(3))) void*)(&As[e]), 16, 0, 0);
        }
#pragma unroll
        for (int c = 0; c < BLOADS; ++c) {
            int e = c * 2048 + tid * 8;
            int row = e >> 5, col = e & 31;
            __builtin_amdgcn_global_load_lds(
                (const __attribute__((address_space(1))) void*)(B + (size_t)(bn * BN + row) * K + k0 + col),
                (__attribute__((address_space(3))) void*)(&Bs[e]), 16, 0, 0);
        }
        __syncthreads();
        short8 af[FM], bfr[FN];
#pragma unroll
        for (int i = 0; i < FM; ++i)
            af[i] = *(const short8*)(&As[(wm * WM + i * 16 + lrow) * BK + lk * 8]);
#pragma unroll
        for (int j = 0; j < FN; ++j)
            bfr[j] = *(const short8*)(&Bs[(wn * WN + j * 16 + lrow) * BK + lk * 8]);
#pragma unroll
        for (int i = 0; i < FM; ++i)
#pragma unroll
            for (int j = 0; j < FN; ++j)
                acc[i][j] = __builtin_amdgcn_mfma_f32_16x16x32_bf16(af[i], bfr[j], acc[i][j], 0, 0, 0);
    }
}

// generic GEMM (compose + final Linear)
template<int BM, int BN, bool OUT_BF16, bool BIAS>
__global__ __launch_bounds__(256) void gemm_bt(
    const u16* __restrict__ A, const u16* __restrict__ B,
    void* __restrict__ Cout, const float* __restrict__ bias, int Nc)
{
    __shared__ __align__(16) u16 As[BM * 32];
    __shared__ __align__(16) u16 Bs[BN * 32];
    constexpr int WM = BM / 2, WN = BN / 2, FM = WM / 16, FN = WN / 16;
    floatx4 acc[FM][FN] = {};
    const int tid = threadIdx.x, bm = blockIdx.x, bn = blockIdx.y;
    gemm_core<BM, BN>(A, B, bm, bn, tid, As, Bs, acc);
    const int wave = tid >> 6, lane = tid & 63, wm = wave >> 1, wn = wave & 1;
    const int lrow = lane & 15, lk = lane >> 4;
#pragma unroll
    for (int i = 0; i < FM; ++i)
#pragma unroll
        for (int j = 0; j < FN; ++j) {
            const int col = bn * BN + wn * WN + j * 16 + lrow;
            const float bv = BIAS ? bias[col] : 0.0f;
#pragma unroll
            for (int r = 0; r < 4; ++r) {
                const int row = bm * BM + wm * WM + i * 16 + lk * 4 + r;
                const float v = acc[i][j][r] + bv;
                if (OUT_BF16) ((u16*)Cout)[(size_t)row * Nc + col] = f2bf(v);
                else          ((float*)Cout)[(size_t)row * Nc + col] = v;
            }
        }
}

// ---------------------------------------------------------------------------
// node GEMM: xb[2048,512] @ Bcat[2048,512]^T, routed epilogue by bn:
//   bn 0..3  -> Hb  (bf16, +bnn)      cols   0..511  (Wnn rows)
//   bn 4..7  -> OUT1 (f32, +bias)     cols 512..1023 (rootT rows)
//   bn 8..15 -> G12 (f32)             cols 1024..2047 (M1;M2 rows)
// ---------------------------------------------------------------------------
__global__ __launch_bounds__(256) void node_gemm(
    const u16* __restrict__ A, const u16* __restrict__ B,
    const float* __restrict__ bnn, const float* __restrict__ bias,
    u16* __restrict__ Hb, float* __restrict__ OUT1, float* __restrict__ G12)
{
    __shared__ __align__(16) u16 As[128 * 32];
    __shared__ __align__(16) u16 Bs[128 * 32];
    floatx4 acc[4][4] = {};
    const int tid = threadIdx.x, bm = blockIdx.x, bn = blockIdx.y;
    gemm_core<128, 128>(A, B, bm, bn, tid, As, Bs, acc);
    const int wave = tid >> 6, lane = tid & 63, wm = wave >> 1, wn = wave & 1;
    const int lrow = lane & 15, lk = lane >> 4;
#pragma unroll
    for (int i = 0; i < 4; ++i)
#pragma unroll
        for (int j = 0; j < 4; ++j) {
            const int colg = bn * 128 + wn * 64 + j * 16 + lrow;
#pragma unroll
            for (int r = 0; r < 4; ++r) {
                const int row = bm * 128 + wm * 64 + i * 16 + lk * 4 + r;
                const float v = acc[i][j][r];
                if (bn < 4) {
                    Hb[(size_t)row * 512 + colg] = f2bf(v + bnn[colg]);
                } else if (bn < 8) {
                    const int c = colg - 512;
                    OUT1[(size_t)row * 512 + c] = v + bias[c];
                } else {
                    G12[(size_t)row * 1024 + (colg - 1024)] = v;
                }
            }
        }
}

// ---------------------------------------------------------------------------
// edge GEMM + fused attention score:
//   acc = ea@M3^T; sval = acc + G1[dst,col] + G2[src,col] + bb[col]
//   sraw[e] += sum_col tanh(sval)*w2[col]   (lane-reduced, atomic partials)
// ---------------------------------------------------------------------------
__global__ __launch_bounds__(256) void edge_gemm_score(
    const u16* __restrict__ A, const u16* __restrict__ B,
    const float* __restrict__ G12, const int* __restrict__ ei,
    const float* __restrict__ bb, const float* __restrict__ w2,
    float* __restrict__ sraw)
{
    __shared__ __align__(16) u16 As[128 * 32];
    __shared__ __align__(16) u16 Bs[128 * 32];
    floatx4 acc[4][4] = {};
    const int tid = threadIdx.x, bm = blockIdx.x, bn = blockIdx.y;
    gemm_core<128, 128>(A, B, bm, bn, tid, As, Bs, acc);
    const int wave = tid >> 6, lane = tid & 63, wm = wave >> 1, wn = wave & 1;
    const int lrow = lane & 15, lk = lane >> 4;
#pragma unroll
    for (int i = 0; i < 4; ++i) {
#pragma unroll
        for (int r = 0; r < 4; ++r) {
            const int e = bm * 128 + wm * 64 + i * 16 + lk * 4 + r;
            const int sn = ei[e], dn = ei[EE + e];
            float sp = 0.0f;
#pragma unroll
            for (int j = 0; j < 4; ++j) {
                const int col = bn * 128 + wn * 64 + j * 16 + lrow;
                const float v = acc[i][j][r]
                              + G12[(size_t)dn * 1024 + col]
                              + G12[(size_t)sn * 1024 + 512 + col]
                              + bb[col];
                sp += tanhf(v) * w2[col];
            }
#pragma unroll
            for (int m = 1; m < 16; m <<= 1) sp += __shfl_xor(sp, m);
            if (lrow == 0) atomicAdd(sraw + e, sp);
        }
    }
}

// ---------------------------------------------------------------------------
// s = leaky_relu(sraw); M = max(s); p = exp(s - M)   (single 1024-thread block)
// ---------------------------------------------------------------------------
__global__ __launch_bounds__(1024) void softmax_prep(
    const float* __restrict__ sraw, float* __restrict__ p)
{
    const int tid = threadIdx.x;
    float sv[8];
    float m = -3.0e38f;
#pragma unroll
    for (int k = 0; k < 8; ++k) {
        float v = sraw[k * 1024 + tid];
        v = (v >= 0.0f) ? v : 0.2f * v;
        sv[k] = v; m = fmaxf(m, v);
    }
    for (int o = 32; o; o >>= 1) m = fmaxf(m, __shfl_down(m, o));
    __shared__ float red[16];
    if ((tid & 63) == 0) red[tid >> 6] = m;
    __syncthreads();
    float M = red[0];
#pragma unroll
    for (int k = 1; k < 16; ++k) M = fmaxf(M, red[k]);
#pragma unroll
    for (int k = 0; k < 8; ++k) p[k * 1024 + tid] = __expf(sv[k] - M);
}

// ---------------------------------------------------------------------------
// att: 4 rows per block; p-chunk registers shared across the 4 mask rows
// ---------------------------------------------------------------------------
__global__ __launch_bounds__(256) void lse_att(
    const unsigned char* __restrict__ mask, const float* __restrict__ p,
    float* __restrict__ att)
{
    const int i0 = blockIdx.x * 4, tid = threadIdx.x;
    float sums[4] = {0.0f, 0.0f, 0.0f, 0.0f};
#pragma unroll
    for (int c = 0; c < 2; ++c) {
        const int base = c * 4096 + tid * 16;
        float pv[16];
#pragma unroll
        for (int q = 0; q < 4; ++q)
            *(float4*)(pv + q * 4) = *(const float4*)(p + base + q * 4);
#pragma unroll
        for (int rr = 0; rr < 4; ++rr) {
            uint4 mw = *(const uint4*)(mask + (size_t)(i0 + rr) * EE + base);
            uint32_t w[4] = { mw.x, mw.y, mw.z, mw.w };
            float s = 0.0f;
#pragma unroll
            for (int q = 0; q < 4; ++q) {
                s += pv[q * 4 + 0] * (float)((w[q]      ) & 1u);
                s += pv[q * 4 + 1] * (float)((w[q] >>  8) & 1u);
                s += pv[q * 4 + 2] * (float)((w[q] >> 16) & 1u);
                s += pv[q * 4 + 3] * (float)((w[q] >> 24) & 1u);
            }
            sums[rr] += s;
        }
    }
#pragma unroll
    for (int rr = 0; rr < 4; ++rr)
        for (int o = 32; o; o >>= 1) sums[rr] += __shfl_down(sums[rr], o);
    __shared__ float red[4][4];
    if ((tid & 63) == 0) {
#pragma unroll
        for (int rr = 0; rr < 4; ++rr) red[rr][tid >> 6] = sums[rr];
    }
    __syncthreads();
    if (tid < 4) {
        const int i = i0 + tid;
        const float total = red[tid][0] + red[tid][1] + red[tid][2] + red[tid][3];
        const unsigned char diag = mask[(size_t)i * EE + i];
        float a;
        if (total > 0.0f) a = diag ? (p[i] / total) : 0.0f;
        else              a = 1.0f / (float)EE;   // all-false row
        att[i] = a;
    }
}

// ---------------------------------------------------------------------------
// scatter: OUT1[dst] += att[e] * H[src]
// ---------------------------------------------------------------------------
__global__ __launch_bounds__(256) void aggr_kernel(
    const u16* __restrict__ Hb, const int* __restrict__ ei,
    const float* __restrict__ att, float* __restrict__ OUT1)
{
    const int e = blockIdx.x;
    const float a = att[e];
    if (a == 0.0f) return;
    const int sn = ei[e], dn = ei[EE + e];
    const u16* h = Hb + (size_t)sn * 512;
    float* o = OUT1 + (size_t)dn * 512;
    const int c = threadIdx.x * 2;
    const uint32_t hv = *(const uint32_t*)(h + c);
    atomicAdd(o + c,     a * bf2f((u16)(hv & 0xffffu)));
    atomicAdd(o + c + 1, a * bf2f((u16)(hv >> 16)));
}

// ---------------------------------------------------------------------------
// LayerNorm over C=512
// ---------------------------------------------------------------------------
template<bool RESID, bool WRITE_BF16>
__global__ __launch_bounds__(256) void ln_kernel(
    const float* __restrict__ in, const float* __restrict__ resid,
    const float* __restrict__ gamma, const float* __restrict__ beta,
    float* __restrict__ outF, u16* __restrict__ outB)
{
    const int n = blockIdx.x, tid = threadIdx.x;
    const size_t rowoff = (size_t)n * 512;
    float2 v = *(const float2*)(in + rowoff + tid * 2);
    float a0 = v.x, a1 = v.y;
    if (RESID) {
        float2 r = *(const float2*)(resid + rowoff + tid * 2);
        a0 += r.x; a1 += r.y;
    }
    float sum = a0 + a1, sq = a0 * a0 + a1 * a1;
    for (int o = 32; o; o >>= 1) { sum += __shfl_down(sum, o); sq += __shfl_down(sq, o); }
    __shared__ float rs_[4], rq_[4];
    if ((tid & 63) == 0) { rs_[tid >> 6] = sum; rq_[tid >> 6] = sq; }
    __syncthreads();
    sum = rs_[0] + rs_[1] + rs_[2] + rs_[3];
    sq  = rq_[0] + rq_[1] + rq_[2] + rq_[3];
    const float mean = sum * (1.0f / 512.0f);
    const float var  = sq * (1.0f / 512.0f) - mean * mean;
    const float rstd = rsqrtf(var + 1e-5f);
    const int c0 = tid * 2;
    const float y0 = (a0 - mean) * rstd * gamma[c0]     + beta[c0];
    const float y1 = (a1 - mean) * rstd * gamma[c0 + 1] + beta[c0 + 1];
    *(float2*)(outF + rowoff + c0) = make_float2(y0, y1);
    if (WRITE_BF16) { outB[rowoff + c0] = f2bf(y0); outB[rowoff + c0 + 1] = f2bf(y1); }
}

// ---------------------------------------------------------------------------
extern "C" void kernel_launch(void* const* d_in, const int* in_sizes, int n_in,
                              void* d_out, int out_size, void* d_ws, size_t ws_size,
                              hipStream_t stream)
{
    const float* x     = (const float*)d_in[0];
    const int*   ei    = (const int*)d_in[1];
    const float* ea    = (const float*)d_in[2];
    const unsigned char* mask = (const unsigned char*)d_in[3];
    const float* Wnn   = (const float*)d_in[4];
    const float* bnn   = (const float*)d_in[5];
    const float* Watt1 = (const float*)d_in[6];
    const float* batt1 = (const float*)d_in[7];
    const float* watt2 = (const float*)d_in[8];
    const float* root  = (const float*)d_in[9];
    const float* bias  = (const float*)d_in[10];
    const float* gam1  = (const float*)d_in[11];
    const float* bet1  = (const float*)d_in[12];
    const float* gam2  = (const float*)d_in[13];
    const float* bet2  = (const float*)d_in[14];
    const float* Wlin  = (const float*)d_in[15];
    const float* blin  = (const float*)d_in[16];
    float* out = (float*)d_out;

    char* w = (char*)d_ws;
    auto take = [&](size_t bytes) -> char* {
        char* pp = w; w += (bytes + 255) & ~(size_t)255; return pp;
    };
    u16*   xb     = (u16*)take((size_t)NN * CD * 2);
    u16*   eb     = (u16*)take((size_t)EE * CD * 2);
    u16*   Wpackb = (u16*)take((size_t)1536 * CD * 2);
    u16*   WnnTb  = (u16*)take((size_t)CD * CD * 2);
    u16*   Wlinb  = (u16*)take((size_t)CD * CD * 2);
    // Bcat rows: [0,512)=Wnn  [512,1024)=root^T  [1024,2560)=MC=[M1;M2;M3]
    u16*   Bcat   = (u16*)take((size_t)2560 * CD * 2);
    u16*   Hb     = (u16*)take((size_t)NN * CD * 2);
    float* G12    = (float*)take((size_t)NN * 1024 * 4);
    float* OUT1   = (float*)take((size_t)NN * CD * 4);
    float* sraw   = (float*)take((size_t)EE * 4);
    float* pbuf   = (float*)take((size_t)EE * 4);
    float* attb   = (float*)take((size_t)EE * 4);
    float* bb     = (float*)take((size_t)CD * 4);
    float* x1     = (float*)take((size_t)NN * CD * 4);
    u16*   x1b    = (u16*)take((size_t)NN * CD * 2);
    float* Tbuf   = (float*)take((size_t)NN * CD * 4);

    hipMemsetAsync(sraw, 0, (size_t)EE * 4, stream);
    // 1. convert/pack
    prep_kernel<<<6912, 256, 0, stream>>>(x, ea, Wnn, Wlin, root, Watt1,
                                          xb, eb, Bcat, WnnTb, Wlinb, Wpackb);
    // 2. bias vector bb = b_att1 + [A1;A2;A3]·bnn3 (f32)
    bbvec_kernel<<<512, 256, 0, stream>>>(Watt1, bnn, batt1, bb);
    // 3. compose MC = Wpack @ Wnn (bf16) -> Bcat rows 1024..2559
    gemm_bt<64, 128, true, false><<<dim3(24, 4), 256, 0, stream>>>(
        Wpackb, WnnTb, Bcat + (size_t)1024 * 512, nullptr, 512);
    // 4. node GEMM: H | OUT1 | G12 in one pass
    node_gemm<<<dim3(16, 16), 256, 0, stream>>>(xb, Bcat, bnn, bias, Hb, OUT1, G12);
    // 5. edge GEMM + fused score partials
    edge_gemm_score<<<dim3(64, 4), 256, 0, stream>>>(
        eb, Bcat + (size_t)2048 * 512, G12, ei, bb, watt2, sraw);
    // 6. leaky + max + exp
    softmax_prep<<<1, 1024, 0, stream>>>(sraw, pbuf);
    // 7. masked-denominator attention (E x E mask scan)
    lse_att<<<2048, 256, 0, stream>>>(mask, pbuf, attb);
    // 8. scatter aggregation into OUT1
    aggr_kernel<<<EE, 256, 0, stream>>>(Hb, ei, attb, OUT1);
    // 9. x1 = LN(OUT1)
    ln_kernel<false, true><<<NN, 256, 0, stream>>>(OUT1, nullptr, gam1, bet1, x1, x1b);
    // 10. T = x1 @ Wlin^T + blin
    gemm_bt<64, 128, false, true><<<dim3(32, 4), 256, 0, stream>>>(x1b, Wlinb, Tbuf, blin, 512);
    // 11. out = LN(x1 + T)
    ln_kernel<true, false><<<NN, 256, 0, stream>>>(Tbuf, x1, gam2, bet2, out, nullptr);
}

// Round 4
// 451.202 us; speedup vs baseline: 1.0308x; 1.0148x over previous
//
#include <hip/hip_runtime.h>
#include <stdint.h>
#include <stddef.h>

// Problem constants: N=2048, C=512, E=8192
#define NN 2048
#define CD 512
#define EE 8192

typedef unsigned short u16;
typedef __attribute__((ext_vector_type(8))) short short8;   // 8 x bf16 MFMA A/B frag
typedef __attribute__((ext_vector_type(4))) float floatx4;  // MFMA C/D frag

__device__ inline u16 f2bf(float f) {
    uint32_t u = __float_as_uint(f);
    u += 0x7FFFu + ((u >> 16) & 1u);   // RNE
    return (u16)(u >> 16);
}
__device__ inline float bf2f(u16 h) { return __uint_as_float(((uint32_t)h) << 16); }

// ---------------------------------------------------------------------------
// prep: bf16 conversions + transposes + W_att1 pack + (appended blocks) bbvec.
// Segments (elems): xb 1048576 | eb 4194304 | Wnn->Bcat[0:512) 262144 |
//   rootT->Bcat[512:1024) 262144 | WnnT 262144 | Wlin 262144 | Wpack 786432
// total 7077888 / 4 per thread = 6912 blocks; blocks [6912,7424) do bbvec.
// ---------------------------------------------------------------------------
__global__ __launch_bounds__(256) void prep_kernel(
    const float* __restrict__ x, const float* __restrict__ ea,
    const float* __restrict__ Wnn, const float* __restrict__ Wlin,
    const float* __restrict__ root, const float* __restrict__ Watt1,
    const float* __restrict__ bnn, const float* __restrict__ batt1,
    u16* __restrict__ xb, u16* __restrict__ eb, u16* __restrict__ Bcat,
    u16* __restrict__ WnnTb, u16* __restrict__ Wlinb, u16* __restrict__ Wpackb,
    float* __restrict__ bb)
{
    if (blockIdx.x >= 6912) {
        // bbvec: bb[c] = b_att1[c] + sum_t Watt1[c,t] * bnn[t%512]  (f32)
        const int c = blockIdx.x - 6912, tid = threadIdx.x;
        const float* row = Watt1 + (size_t)c * 1536;
        float partial = 0.0f;
#pragma unroll
        for (int t = tid; t < 1536; t += 256) partial += row[t] * bnn[t & 511];
        for (int o = 32; o; o >>= 1) partial += __shfl_down(partial, o);
        __shared__ float red[4];
        if ((tid & 63) == 0) red[tid >> 6] = partial;
        __syncthreads();
        if (tid == 0) bb[c] = batt1[c] + red[0] + red[1] + red[2] + red[3];
        return;
    }
    size_t i4 = ((size_t)blockIdx.x * 256 + threadIdx.x) * 4;
    auto cvt4 = [](const float* src, u16* dst, size_t idx) {
        float4 v = *(const float4*)(src + idx);
        ushort4 o; o.x = f2bf(v.x); o.y = f2bf(v.y); o.z = f2bf(v.z); o.w = f2bf(v.w);
        *(ushort4*)(dst + idx) = o;
    };
    if (i4 < 1048576) { cvt4(x, xb, i4); return; }
    i4 -= 1048576;
    if (i4 < 4194304) { cvt4(ea, eb, i4); return; }
    i4 -= 4194304;
    if (i4 < 262144) { cvt4(Wnn, Bcat, i4); return; }          // Bcat rows 0..511 = Wnn
    i4 -= 262144;
    if (i4 < 262144) {                                          // Bcat rows 512..1023 = root^T
        int c = (int)(i4 >> 9), k = (int)(i4 & 511);
        ushort4 o;
        o.x = f2bf(root[(size_t)(k + 0) * 512 + c]);
        o.y = f2bf(root[(size_t)(k + 1) * 512 + c]);
        o.z = f2bf(root[(size_t)(k + 2) * 512 + c]);
        o.w = f2bf(root[(size_t)(k + 3) * 512 + c]);
        *(ushort4*)(Bcat + 262144 + i4) = o; return;
    }
    i4 -= 262144;
    if (i4 < 262144) {                                          // WnnT[k][t] = Wnn[t][k]
        int k = (int)(i4 >> 9), t = (int)(i4 & 511);
        ushort4 o;
        o.x = f2bf(Wnn[(size_t)(t + 0) * 512 + k]);
        o.y = f2bf(Wnn[(size_t)(t + 1) * 512 + k]);
        o.z = f2bf(Wnn[(size_t)(t + 2) * 512 + k]);
        o.w = f2bf(Wnn[(size_t)(t + 3) * 512 + k]);
        *(ushort4*)(WnnTb + i4) = o; return;
    }
    i4 -= 262144;
    if (i4 < 262144) { cvt4(Wlin, Wlinb, i4); return; }
    i4 -= 262144;
    {   // Wpack[cp][t] = Watt1[cp&511][(cp>>9)*512 + t]  (rows: A1(512); A2(512); A3(512))
        int cp = (int)(i4 >> 9), t = (int)(i4 & 511);
        const float* sp = Watt1 + (size_t)(cp & 511) * 1536 + (cp >> 9) * 512 + t;
        float4 v = *(const float4*)sp;
        ushort4 o; o.x = f2bf(v.x); o.y = f2bf(v.y); o.z = f2bf(v.z); o.w = f2bf(v.w);
        *(ushort4*)(Wpackb + i4) = o;
    }
}

// ---------------------------------------------------------------------------
// shared MFMA K-loop: acc += A_tile * B_tile^T over K=512, BK=32.
// Wave grid WR x WC (WR*WC==4). Handles fractional staging via wave-uniform
// tid guards (ATH/BTH are multiples of 64).
// ---------------------------------------------------------------------------
template<int BM, int BN, int WR, int WC>
__device__ inline void gemm_core(const u16* __restrict__ A, const u16* __restrict__ B,
                                 int bm, int bn, int tid, u16* As, u16* Bs,
                                 floatx4 (&acc)[(BM / WR) / 16][(BN / WC) / 16])
{
    constexpr int K = 512, BK = 32;
    constexpr int WM = BM / WR, WN = BN / WC;
    constexpr int FM = WM / 16, FN = WN / 16;
    constexpr int ATH = BM * BK / 8;   // threads needed for A (8 elems = 16B each)
    constexpr int BTH = BN * BK / 8;
    const int wave = tid >> 6, lane = tid & 63;
    const int wm = wave / WC, wn = wave % WC;
    const int lrow = lane & 15, lk = lane >> 4;
    for (int k0 = 0; k0 < K; k0 += BK) {
        __syncthreads();
        if constexpr (ATH >= 256) {
#pragma unroll
            for (int c = 0; c < ATH / 256; ++c) {
                int e = c * 2048 + tid * 8;
                int row = e >> 5, col = e & 31;
                __builtin_amdgcn_global_load_lds(
                    (const __attribute__((address_space(1))) void*)(A + (size_t)(bm * BM + row) * K + k0 + col),
                    (__attribute__((address_space(3))) void*)(&As[e]), 16, 0, 0);
            }
        } else {
            if (tid < ATH) {
                int e = tid * 8;
                int row = e >> 5, col = e & 31;
                __builtin_amdgcn_global_load_lds(
                    (const __attribute__((address_space(1))) void*)(A + (size_t)(bm * BM + row) * K + k0 + col),
                    (__attribute__((address_space(3))) void*)(&As[e]), 16, 0, 0);
            }
        }
        if constexpr (BTH >= 256) {
#pragma unroll
            for (int c = 0; c < BTH / 256; ++c) {
                int e = c * 2048 + tid * 8;
                int row = e >> 5, col = e & 31;
                __builtin_amdgcn_global_load_lds(
                    (const __attribute__((address_space(1))) void*)(B + (size_t)(bn * BN + row) * K + k0 + col),
                    (__attribute__((address_space(3))) void*)(&Bs[e]), 16, 0, 0);
            }
        } else {
            if (tid < BTH) {
                int e = tid * 8;
                int row = e >> 5, col = e & 31;
                __builtin_amdgcn_global_load_lds(
                    (const __attribute__((address_space(1))) void*)(B + (size_t)(bn * BN + row) * K + k0 + col),
                    (__attribute__((address_space(3))) void*)(&Bs[e]), 16, 0, 0);
            }
        }
        __syncthreads();
        short8 af[FM], bfr[FN];
#pragma unroll
        for (int i = 0; i < FM; ++i)
            af[i] = *(const short8*)(&As[(wm * WM + i * 16 + lrow) * BK + lk * 8]);
#pragma unroll
        for (int j = 0; j < FN; ++j)
            bfr[j] = *(const short8*)(&Bs[(wn * WN + j * 16 + lrow) * BK + lk * 8]);
#pragma unroll
        for (int i = 0; i < FM; ++i)
#pragma unroll
            for (int j = 0; j < FN; ++j)
                acc[i][j] = __builtin_amdgcn_mfma_f32_16x16x32_bf16(af[i], bfr[j], acc[i][j], 0, 0, 0);
    }
}

// generic GEMM (compose only now)
template<int BM, int BN, bool OUT_BF16, bool BIAS>
__global__ __launch_bounds__(256) void gemm_bt(
    const u16* __restrict__ A, const u16* __restrict__ B,
    void* __restrict__ Cout, const float* __restrict__ bias, int Nc)
{
    __shared__ __align__(16) u16 As[BM * 32];
    __shared__ __align__(16) u16 Bs[BN * 32];
    constexpr int FM = (BM / 2) / 16, FN = (BN / 2) / 16;
    floatx4 acc[FM][FN] = {};
    const int tid = threadIdx.x, bm = blockIdx.x, bn = blockIdx.y;
    gemm_core<BM, BN, 2, 2>(A, B, bm, bn, tid, As, Bs, acc);
    const int wave = tid >> 6, lane = tid & 63, wm = wave >> 1, wn = wave & 1;
    const int lrow = lane & 15, lk = lane >> 4;
#pragma unroll
    for (int i = 0; i < FM; ++i)
#pragma unroll
        for (int j = 0; j < FN; ++j) {
            const int col = bn * BN + wn * (BN / 2) + j * 16 + lrow;
            const float bv = BIAS ? bias[col] : 0.0f;
#pragma unroll
            for (int r = 0; r < 4; ++r) {
                const int row = bm * BM + wm * (BM / 2) + i * 16 + lk * 4 + r;
                const float v = acc[i][j][r] + bv;
                if (OUT_BF16) ((u16*)Cout)[(size_t)row * Nc + col] = f2bf(v);
                else          ((float*)Cout)[(size_t)row * Nc + col] = v;
            }
        }
}

// ---------------------------------------------------------------------------
// node GEMM: xb[2048,512] @ Bcat[2048,512]^T, routed epilogue by bn:
//   bn 0..3  -> Hb (bf16,+bnn) | bn 4..7 -> OUT1 (f32,+bias) | bn 8..15 -> G12
// ---------------------------------------------------------------------------
__global__ __launch_bounds__(256) void node_gemm(
    const u16* __restrict__ A, const u16* __restrict__ B,
    const float* __restrict__ bnn, const float* __restrict__ bias,
    u16* __restrict__ Hb, float* __restrict__ OUT1, float* __restrict__ G12)
{
    __shared__ __align__(16) u16 As[128 * 32];
    __shared__ __align__(16) u16 Bs[128 * 32];
    floatx4 acc[4][4] = {};
    const int tid = threadIdx.x, bm = blockIdx.x, bn = blockIdx.y;
    gemm_core<128, 128, 2, 2>(A, B, bm, bn, tid, As, Bs, acc);
    const int wave = tid >> 6, lane = tid & 63, wm = wave >> 1, wn = wave & 1;
    const int lrow = lane & 15, lk = lane >> 4;
#pragma unroll
    for (int i = 0; i < 4; ++i)
#pragma unroll
        for (int j = 0; j < 4; ++j) {
            const int colg = bn * 128 + wn * 64 + j * 16 + lrow;
#pragma unroll
            for (int r = 0; r < 4; ++r) {
                const int row = bm * 128 + wm * 64 + i * 16 + lk * 4 + r;
                const float v = acc[i][j][r];
                if (bn < 4) {
                    Hb[(size_t)row * 512 + colg] = f2bf(v + bnn[colg]);
                } else if (bn < 8) {
                    const int c = colg - 512;
                    OUT1[(size_t)row * 512 + c] = v + bias[c];
                } else {
                    G12[(size_t)row * 1024 + (colg - 1024)] = v;
                }
            }
        }
}

// ---------------------------------------------------------------------------
// edge GEMM (full-row tile 32x512) + fused score, no atomics:
//   s[e] = leaky( sum_col tanh(E3[e,col] + G1[dst]+G2[src]+bb) * w2[col] )
// ---------------------------------------------------------------------------
__global__ __launch_bounds__(256) void edge_gemm_score(
    const u16* __restrict__ A, const u16* __restrict__ B,
    const float* __restrict__ G12, const int* __restrict__ ei,
    const float* __restrict__ bb, const float* __restrict__ w2,
    float* __restrict__ sOut)
{
    __shared__ __align__(16) u16 As[32 * 32];
    __shared__ __align__(16) u16 Bs[512 * 32];
    __shared__ float sred[32][4];
    floatx4 acc[2][8] = {};
    const int tid = threadIdx.x, bm = blockIdx.x;
    gemm_core<32, 512, 1, 4>(A, B, bm, 0, tid, As, Bs, acc);
    const int wave = tid >> 6, lane = tid & 63;
    const int lrow = lane & 15, lk = lane >> 4;
#pragma unroll
    for (int i = 0; i < 2; ++i) {
#pragma unroll
        for (int r = 0; r < 4; ++r) {
            const int e = bm * 32 + i * 16 + lk * 4 + r;
            const int sn = ei[e], dn = ei[EE + e];
            const float* gd = G12 + (size_t)dn * 1024;
            const float* gs = G12 + (size_t)sn * 1024 + 512;
            float sp = 0.0f;
#pragma unroll
            for (int j = 0; j < 8; ++j) {
                const int col = wave * 128 + j * 16 + lrow;
                const float v = acc[i][j][r] + gd[col] + gs[col] + bb[col];
                sp += tanhf(v) * w2[col];
            }
#pragma unroll
            for (int m = 1; m < 16; m <<= 1) sp += __shfl_xor(sp, m);
            if (lrow == 0) sred[i * 16 + lk * 4 + r][wave] = sp;
        }
    }
    __syncthreads();
    if (tid < 32) {
        float s = sred[tid][0] + sred[tid][1] + sred[tid][2] + sred[tid][3];
        sOut[bm * 32 + tid] = (s >= 0.0f) ? s : 0.2f * s;  // leaky_relu folded in
    }
}

// ---------------------------------------------------------------------------
// fused att + scatter: 4 mask rows per block.
// p_j = exp(s_j) inline (no global max needed: |s| bounded ~sum|w2| << 88).
// att_i = diag ? p_i/total : 0 ; then OUT1[dst_e] += att_e * H[src_e].
// ---------------------------------------------------------------------------
__global__ __launch_bounds__(256) void lse_att_aggr(
    const unsigned char* __restrict__ mask, const float* __restrict__ s,
    const int* __restrict__ ei, const u16* __restrict__ Hb,
    float* __restrict__ OUT1)
{
    const int i0 = blockIdx.x * 4, tid = threadIdx.x;
    float sums[4] = {0.0f, 0.0f, 0.0f, 0.0f};
#pragma unroll
    for (int c = 0; c < 2; ++c) {
        const int base = c * 4096 + tid * 16;
        float pv[16];
#pragma unroll
        for (int q = 0; q < 4; ++q) {
            float4 sv = *(const float4*)(s + base + q * 4);
            pv[q * 4 + 0] = __expf(sv.x); pv[q * 4 + 1] = __expf(sv.y);
            pv[q * 4 + 2] = __expf(sv.z); pv[q * 4 + 3] = __expf(sv.w);
        }
#pragma unroll
        for (int rr = 0; rr < 4; ++rr) {
            uint4 mw = *(const uint4*)(mask + (size_t)(i0 + rr) * EE + base);
            uint32_t w[4] = { mw.x, mw.y, mw.z, mw.w };
            float acc = 0.0f;
#pragma unroll
            for (int q = 0; q < 4; ++q) {
                acc += pv[q * 4 + 0] * (float)((w[q]      ) & 1u);
                acc += pv[q * 4 + 1] * (float)((w[q] >>  8) & 1u);
                acc += pv[q * 4 + 2] * (float)((w[q] >> 16) & 1u);
                acc += pv[q * 4 + 3] * (float)((w[q] >> 24) & 1u);
            }
            sums[rr] += acc;
        }
    }
#pragma unroll
    for (int rr = 0; rr < 4; ++rr)
        for (int o = 32; o; o >>= 1) sums[rr] += __shfl_down(sums[rr], o);
    __shared__ float red[4][4];
    __shared__ float attv[4];
    if ((tid & 63) == 0) {
#pragma unroll
        for (int rr = 0; rr < 4; ++rr) red[rr][tid >> 6] = sums[rr];
    }
    __syncthreads();
    if (tid < 4) {
        const int i = i0 + tid;
        const float total = red[tid][0] + red[tid][1] + red[tid][2] + red[tid][3];
        const unsigned char diag = mask[(size_t)i * EE + i];
        float a;
        if (total > 0.0f) a = diag ? (__expf(s[i]) / total) : 0.0f;
        else              a = 1.0f / (float)EE;   // all-false row edge case
        attv[tid] = a;
    }
    __syncthreads();
#pragma unroll
    for (int rr = 0; rr < 4; ++rr) {
        const float a = attv[rr];
        if (a == 0.0f) continue;
        const int e = i0 + rr;
        const int sn = ei[e], dn = ei[EE + e];
        const u16* h = Hb + (size_t)sn * 512;
        float* o = OUT1 + (size_t)dn * 512;
        const int c2 = tid * 2;
        const uint32_t hv = *(const uint32_t*)(h + c2);
        atomicAdd(o + c2,     a * bf2f((u16)(hv & 0xffffu)));
        atomicAdd(o + c2 + 1, a * bf2f((u16)(hv >> 16)));
    }
}

// ---------------------------------------------------------------------------
// LayerNorm over C=512 (x1 = LN(OUT1), f32 + bf16 copies)
// ---------------------------------------------------------------------------
template<bool RESID, bool WRITE_BF16>
__global__ __launch_bounds__(256) void ln_kernel(
    const float* __restrict__ in, const float* __restrict__ resid,
    const float* __restrict__ gamma, const float* __restrict__ beta,
    float* __restrict__ outF, u16* __restrict__ outB)
{
    const int n = blockIdx.x, tid = threadIdx.x;
    const size_t rowoff = (size_t)n * 512;
    float2 v = *(const float2*)(in + rowoff + tid * 2);
    float a0 = v.x, a1 = v.y;
    if (RESID) {
        float2 r = *(const float2*)(resid + rowoff + tid * 2);
        a0 += r.x; a1 += r.y;
    }
    float sum = a0 + a1, sq = a0 * a0 + a1 * a1;
    for (int o = 32; o; o >>= 1) { sum += __shfl_down(sum, o); sq += __shfl_down(sq, o); }
    __shared__ float rs_[4], rq_[4];
    if ((tid & 63) == 0) { rs_[tid >> 6] = sum; rq_[tid >> 6] = sq; }
    __syncthreads();
    sum = rs_[0] + rs_[1] + rs_[2] + rs_[3];
    sq  = rq_[0] + rq_[1] + rq_[2] + rq_[3];
    const float mean = sum * (1.0f / 512.0f);
    const float var  = sq * (1.0f / 512.0f) - mean * mean;
    const float rstd = rsqrtf(var + 1e-5f);
    const int c0 = tid * 2;
    const float y0 = (a0 - mean) * rstd * gamma[c0]     + beta[c0];
    const float y1 = (a1 - mean) * rstd * gamma[c0 + 1] + beta[c0 + 1];
    *(float2*)(outF + rowoff + c0) = make_float2(y0, y1);
    if (WRITE_BF16) { outB[rowoff + c0] = f2bf(y0); outB[rowoff + c0 + 1] = f2bf(y1); }
}

// ---------------------------------------------------------------------------
// final Linear + LN2 fused: tile 16 rows x full 512 cols.
//   T = x1b @ Wlin^T + blin ; out = LN(x1 + T) -- row stats in-block.
// ---------------------------------------------------------------------------
__global__ __launch_bounds__(256) void lin_ln2(
    const u16* __restrict__ x1b, const u16* __restrict__ Wlinb,
    const float* __restrict__ x1, const float* __restrict__ blin,
    const float* __restrict__ gam2, const float* __restrict__ bet2,
    float* __restrict__ out)
{
    __shared__ __align__(16) u16 As[16 * 32];
    __shared__ __align__(16) u16 Bs[512 * 32];
    __shared__ float rsum[4][16], rsq[4][16], rmean[16], rrstd[16];
    floatx4 acc[1][8] = {};
    const int tid = threadIdx.x, bm = blockIdx.x;
    gemm_core<16, 512, 1, 4>(x1b, Wlinb, bm, 0, tid, As, Bs, acc);
    const int wave = tid >> 6, lane = tid & 63;
    const int lrow = lane & 15, lk = lane >> 4;
    float psum[4] = {0, 0, 0, 0}, psq[4] = {0, 0, 0, 0};
#pragma unroll
    for (int j = 0; j < 8; ++j) {
        const int col = wave * 128 + j * 16 + lrow;
        const float bl = blin[col];
#pragma unroll
        for (int r = 0; r < 4; ++r) {
            const int grow = bm * 16 + lk * 4 + r;
            const float v = acc[0][j][r] + bl + x1[(size_t)grow * 512 + col];
            acc[0][j][r] = v;
            psum[r] += v; psq[r] += v * v;
        }
    }
#pragma unroll
    for (int r = 0; r < 4; ++r) {
#pragma unroll
        for (int m = 1; m < 16; m <<= 1) {
            psum[r] += __shfl_xor(psum[r], m);
            psq[r]  += __shfl_xor(psq[r], m);
        }
        if (lrow == 0) { rsum[wave][lk * 4 + r] = psum[r]; rsq[wave][lk * 4 + r] = psq[r]; }
    }
    __syncthreads();
    if (tid < 16) {
        const float sm = rsum[0][tid] + rsum[1][tid] + rsum[2][tid] + rsum[3][tid];
        const float sq = rsq[0][tid] + rsq[1][tid] + rsq[2][tid] + rsq[3][tid];
        const float mean = sm * (1.0f / 512.0f);
        const float var  = sq * (1.0f / 512.0f) - mean * mean;
        rmean[tid] = mean;
        rrstd[tid] = rsqrtf(var + 1e-5f);
    }
    __syncthreads();
#pragma unroll
    for (int j = 0; j < 8; ++j) {
        const int col = wave * 128 + j * 16 + lrow;
        const float g = gam2[col], b = bet2[col];
#pragma unroll
        for (int r = 0; r < 4; ++r) {
            const int row16 = lk * 4 + r;
            out[(size_t)(bm * 16 + row16) * 512 + col] =
                (acc[0][j][r] - rmean[row16]) * rrstd[row16] * g + b;
        }
    }
}

// ---------------------------------------------------------------------------
extern "C" void kernel_launch(void* const* d_in, const int* in_sizes, int n_in,
                              void* d_out, int out_size, void* d_ws, size_t ws_size,
                              hipStream_t stream)
{
    const float* x     = (const float*)d_in[0];
    const int*   ei    = (const int*)d_in[1];
    const float* ea    = (const float*)d_in[2];
    const unsigned char* mask = (const unsigned char*)d_in[3];
    const float* Wnn   = (const float*)d_in[4];
    const float* bnn   = (const float*)d_in[5];
    const float* Watt1 = (const float*)d_in[6];
    const float* batt1 = (const float*)d_in[7];
    const float* watt2 = (const float*)d_in[8];
    const float* root  = (const float*)d_in[9];
    const float* bias  = (const float*)d_in[10];
    const float* gam1  = (const float*)d_in[11];
    const float* bet1  = (const float*)d_in[12];
    const float* gam2  = (const float*)d_in[13];
    const float* bet2  = (const float*)d_in[14];
    const float* Wlin  = (const float*)d_in[15];
    const float* blin  = (const float*)d_in[16];
    float* out = (float*)d_out;

    char* w = (char*)d_ws;
    auto take = [&](size_t bytes) -> char* {
        char* pp = w; w += (bytes + 255) & ~(size_t)255; return pp;
    };
    u16*   xb     = (u16*)take((size_t)NN * CD * 2);
    u16*   eb     = (u16*)take((size_t)EE * CD * 2);
    u16*   Wpackb = (u16*)take((size_t)1536 * CD * 2);
    u16*   WnnTb  = (u16*)take((size_t)CD * CD * 2);
    u16*   Wlinb  = (u16*)take((size_t)CD * CD * 2);
    // Bcat rows: [0,512)=Wnn  [512,1024)=root^T  [1024,2560)=MC=[M1;M2;M3]
    u16*   Bcat   = (u16*)take((size_t)2560 * CD * 2);
    u16*   Hb     = (u16*)take((size_t)NN * CD * 2);
    float* G12    = (float*)take((size_t)NN * 1024 * 4);
    float* OUT1   = (float*)take((size_t)NN * CD * 4);
    float* sbuf   = (float*)take((size_t)EE * 4);
    float* bb     = (float*)take((size_t)CD * 4);
    float* x1     = (float*)take((size_t)NN * CD * 4);
    u16*   x1b    = (u16*)take((size_t)NN * CD * 2);

    // 1. convert/pack + bbvec
    prep_kernel<<<7424, 256, 0, stream>>>(x, ea, Wnn, Wlin, root, Watt1, bnn, batt1,
                                          xb, eb, Bcat, WnnTb, Wlinb, Wpackb, bb);
    // 2. compose MC = Wpack @ Wnn (bf16) -> Bcat rows 1024..2559
    gemm_bt<64, 128, true, false><<<dim3(24, 4), 256, 0, stream>>>(
        Wpackb, WnnTb, Bcat + (size_t)1024 * 512, nullptr, 512);
    // 3. node GEMM: H | OUT1 | G12 in one pass
    node_gemm<<<dim3(16, 16), 256, 0, stream>>>(xb, Bcat, bnn, bias, Hb, OUT1, G12);
    // 4. edge GEMM + fused score (full-row tile, writes s directly)
    edge_gemm_score<<<256, 256, 0, stream>>>(
        eb, Bcat + (size_t)2048 * 512, G12, ei, bb, watt2, sbuf);
    // 5. masked-denominator attention + scatter aggregation (exp inline)
    lse_att_aggr<<<2048, 256, 0, stream>>>(mask, sbuf, ei, Hb, OUT1);
    // 6. x1 = LN(OUT1)
    ln_kernel<false, true><<<NN, 256, 0, stream>>>(OUT1, nullptr, gam1, bet1, x1, x1b);
    // 7. out = LN(x1 + x1@Wlin^T + blin)  (GEMM + LN2 fused)
    lin_ln2<<<128, 256, 0, stream>>>(x1b, Wlinb, x1, blin, gam2, bet2, out);
}